// Round 1
// baseline (1122.638 us; speedup 1.0000x reference)
//
#include <hip/hip_runtime.h>

typedef unsigned int uint;
typedef unsigned short ushort_t;

// ---------- bf16 helpers (OCP bfloat16 via bit ops, RNE) ----------
__device__ __forceinline__ ushort_t f2bf(float f) {
  uint u = __builtin_bit_cast(uint, f);
  u += 0x7fffu + ((u >> 16) & 1u);
  return (ushort_t)(u >> 16);
}
__device__ __forceinline__ float bf2f(ushort_t s) {
  return __builtin_bit_cast(float, (uint)s << 16);
}
__device__ __forceinline__ float bflo(uint u) { return __builtin_bit_cast(float, u << 16); }
__device__ __forceinline__ float bfhi(uint u) { return __builtin_bit_cast(float, u & 0xffff0000u); }

struct F8 { float v[8]; };
__device__ __forceinline__ F8 unpack8(uint4 u) {
  F8 r;
  r.v[0] = bflo(u.x); r.v[1] = bfhi(u.x);
  r.v[2] = bflo(u.y); r.v[3] = bfhi(u.y);
  r.v[4] = bflo(u.z); r.v[5] = bfhi(u.z);
  r.v[6] = bflo(u.w); r.v[7] = bfhi(u.w);
  return r;
}

// ---------- Kernel 1: depthwise conv 3x3 stride2 pad1 + LayerNorm ----------
// grid 8*784 blocks, 384 threads (thread = channel)
__global__ __launch_bounds__(384) void k_convln(
    const float* __restrict__ x, const float* __restrict__ wc,
    const float* __restrict__ g, const float* __restrict__ bb,
    float* __restrict__ qout)
{
  const int b  = blockIdx.x / 784;
  const int t  = blockIdx.x % 784;
  const int oy = t / 28, ox = t % 28;
  const int c  = threadIdx.x;
  const float* xb = x + (size_t)b * 3136 * 384 + c;
  float acc = 0.f;
  #pragma unroll
  for (int ky = 0; ky < 3; ky++) {
    const int iy = 2 * oy - 1 + ky;
    if (iy < 0 || iy >= 56) continue;
    #pragma unroll
    for (int kx = 0; kx < 3; kx++) {
      const int ix = 2 * ox - 1 + kx;
      if (ix < 0 || ix >= 56) continue;
      acc += wc[c * 9 + ky * 3 + kx] * xb[(size_t)(iy * 56 + ix) * 384];
    }
  }
  float s = acc, s2 = acc * acc;
  #pragma unroll
  for (int off = 32; off >= 1; off >>= 1) {
    s  += __shfl_xor(s,  off);
    s2 += __shfl_xor(s2, off);
  }
  __shared__ float ps[6], ps2[6];
  if ((c & 63) == 0) { ps[c >> 6] = s; ps2[c >> 6] = s2; }
  __syncthreads();
  float S = 0.f, S2 = 0.f;
  #pragma unroll
  for (int i = 0; i < 6; i++) { S += ps[i]; S2 += ps2[i]; }
  const float mu  = S * (1.f / 384.f);
  const float var = S2 * (1.f / 384.f) - mu * mu;
  const float inv = rsqrtf(var + 1e-5f);
  qout[((size_t)b * 784 + t) * 384 + c] = (acc - mu) * inv * g[c] + bb[c];
}

// ---------- Kernel 2: 2x2 average pool ----------
// exactly 8*784*384 = 2408448 = 9408 * 256 threads
__global__ __launch_bounds__(256) void k_pool(
    const float* __restrict__ x, float* __restrict__ kvout)
{
  const int idx = blockIdx.x * 256 + threadIdx.x;
  const int c = idx % 384;
  const int t = (idx / 384) % 784;
  const int b = idx / (384 * 784);
  const int ty = t / 28, tx = t % 28;
  const float* xb = x + (size_t)b * 3136 * 384 + c;
  const int r0 = (2 * ty) * 56 + 2 * tx;
  const float v = xb[(size_t)r0 * 384] + xb[(size_t)(r0 + 1) * 384]
                + xb[(size_t)(r0 + 56) * 384] + xb[(size_t)(r0 + 57) * 384];
  kvout[idx] = v * 0.25f;
}

// ---------- Kernel 3: Y[m,n] = sum_k X[m,k]*W[n,k] (+bias), fp32 acc ----------
// 64x64 tile, 256 threads, 4x4 microtile. OBF16: emit bf16, else fp32.
template<bool OBF16, bool BIAS>
__global__ __launch_bounds__(256) void k_gemm_xt(
    const float* __restrict__ X, const float* __restrict__ W,
    const float* __restrict__ bias, void* __restrict__ Yv,
    int M, int N, int K)
{
  __shared__ float Xs[64][17];
  __shared__ float Ws[64][17];
  const int tid = threadIdx.x;
  const int n0 = blockIdx.x * 64;
  const int m0 = blockIdx.y * 64;
  const int tx = tid & 15, ty = tid >> 4;
  const int lr = tid >> 2, lc = (tid & 3) << 2;
  float acc[4][4] = {};
  for (int k0 = 0; k0 < K; k0 += 16) {
    __syncthreads();
    const float4 xv = *(const float4*)(X + (size_t)(m0 + lr) * K + k0 + lc);
    const float4 wv = *(const float4*)(W + (size_t)(n0 + lr) * K + k0 + lc);
    Xs[lr][lc + 0] = xv.x; Xs[lr][lc + 1] = xv.y; Xs[lr][lc + 2] = xv.z; Xs[lr][lc + 3] = xv.w;
    Ws[lr][lc + 0] = wv.x; Ws[lr][lc + 1] = wv.y; Ws[lr][lc + 2] = wv.z; Ws[lr][lc + 3] = wv.w;
    __syncthreads();
    #pragma unroll
    for (int kk = 0; kk < 16; kk++) {
      float a0 = Xs[ty * 4 + 0][kk], a1 = Xs[ty * 4 + 1][kk];
      float a2 = Xs[ty * 4 + 2][kk], a3 = Xs[ty * 4 + 3][kk];
      float b0 = Ws[tx * 4 + 0][kk], b1 = Ws[tx * 4 + 1][kk];
      float b2 = Ws[tx * 4 + 2][kk], b3 = Ws[tx * 4 + 3][kk];
      acc[0][0] += a0 * b0; acc[0][1] += a0 * b1; acc[0][2] += a0 * b2; acc[0][3] += a0 * b3;
      acc[1][0] += a1 * b0; acc[1][1] += a1 * b1; acc[1][2] += a1 * b2; acc[1][3] += a1 * b3;
      acc[2][0] += a2 * b0; acc[2][1] += a2 * b1; acc[2][2] += a2 * b2; acc[2][3] += a2 * b3;
      acc[3][0] += a3 * b0; acc[3][1] += a3 * b1; acc[3][2] += a3 * b2; acc[3][3] += a3 * b3;
    }
  }
  #pragma unroll
  for (int i = 0; i < 4; i++) {
    const int m = m0 + ty * 4 + i;
    #pragma unroll
    for (int j = 0; j < 4; j++) {
      const int n = n0 + tx * 4 + j;
      float v = acc[i][j];
      if constexpr (BIAS) v += bias[n];
      if constexpr (OBF16) ((ushort_t*)Yv)[(size_t)m * N + n] = f2bf(v);
      else                 ((float*)Yv)[(size_t)m * N + n] = v;
    }
  }
}

// ---------- Kernel 4: fused attention ----------
// One WG per (b, 4 consecutive l rows). All 6 heads' score rows live in LDS
// (bf16). Phases: QK^T -> fuse(+bilinear res_attn) -> softmax -> PV.
__global__ __launch_bounds__(256) void k_attn(
    const ushort_t* __restrict__ Qb,   // (8,784,384) bf16
    const ushort_t* __restrict__ Kb,
    const ushort_t* __restrict__ Vb,
    const float* __restrict__ res_attn, // (8,6,196,784) f32
    const float* __restrict__ w_fuse,   // (6,12)
    const float* __restrict__ b_fuse,   // (6)
    float* __restrict__ Opre)           // (8,784,384) f32
{
  __shared__ ushort_t Ssc[6][4][784];   // 37632 B  scores (bf16)
  __shared__ ushort_t Qs[4][384];       //  3072 B
  __shared__ ushort_t KVs[28][392];     // 21952 B  (row pad: 784B stride)
  __shared__ float wf[72];
  __shared__ float bfu[6];
  __shared__ float rowsum[24];

  const int tid = threadIdx.x;
  const int b   = blockIdx.x / 196;
  const int l0  = (blockIdx.x % 196) * 4;

  if (tid < 72) wf[tid] = w_fuse[tid];
  if (tid < 6)  bfu[tid] = b_fuse[tid];
  if (tid < 192) {
    const uint4* src = (const uint4*)(Qb + ((size_t)b * 784 + l0) * 384);
    ((uint4*)Qs)[tid] = src[tid];
  }

  // ---- phase 1: S[c][l][t] = scale * Q[l,c*64:].K[t,c*64:] ----
  const int  s_c  = tid / 28;
  const int  s_l2 = (tid % 28) / 14;
  const int  s_t2 = tid % 14;
  const bool s_act = (tid < 168);
  const float scale = 0.05103103630798288f; // 384^-0.5
  const size_t kvbase = (size_t)b * 784 * 384;

  for (int kt = 0; kt < 28; kt++) {
    const int t0 = kt * 28;
    __syncthreads();
    {
      const uint4* src = (const uint4*)(Kb + kvbase) + (size_t)t0 * 48;
      for (int i = tid; i < 1344; i += 256) {
        const int r = i / 48, cc = i % 48;
        ((uint4*)&KVs[r][0])[cc] = src[i];
      }
    }
    __syncthreads();
    if (s_act) {
      float a00 = 0.f, a01 = 0.f, a10 = 0.f, a11 = 0.f;
      const uint4* q0p = (const uint4*)&Qs[s_l2][s_c * 64];
      const uint4* q1p = (const uint4*)&Qs[s_l2 + 2][s_c * 64];
      const uint4* k0p = (const uint4*)&KVs[s_t2][s_c * 64];
      const uint4* k1p = (const uint4*)&KVs[s_t2 + 14][s_c * 64];
      #pragma unroll
      for (int d = 0; d < 8; d++) {
        const F8 qa = unpack8(q0p[d]);
        const F8 qb = unpack8(q1p[d]);
        const F8 ka = unpack8(k0p[d]);
        const F8 kb = unpack8(k1p[d]);
        #pragma unroll
        for (int e = 0; e < 8; e++) {
          a00 += qa.v[e] * ka.v[e];
          a01 += qa.v[e] * kb.v[e];
          a10 += qb.v[e] * ka.v[e];
          a11 += qb.v[e] * kb.v[e];
        }
      }
      Ssc[s_c][s_l2    ][t0 + s_t2     ] = f2bf(a00 * scale);
      Ssc[s_c][s_l2    ][t0 + s_t2 + 14] = f2bf(a01 * scale);
      Ssc[s_c][s_l2 + 2][t0 + s_t2     ] = f2bf(a10 * scale);
      Ssc[s_c][s_l2 + 2][t0 + s_t2 + 14] = f2bf(a11 * scale);
    }
  }
  __syncthreads();

  // ---- phase 2: fuse heads + bilinear-upsampled res_attn (in place) ----
  {
    const float* ra = res_attn + (size_t)b * 6 * 196 * 784;
    for (int idx = tid; idx < 3136; idx += 256) {
      const int l = idx / 784, t = idx % 784;
      const int L = l0 + l;
      const int Yc = L / 28, Xc = L % 28;
      const float cy = fminf(fmaxf((float)Yc * 0.5f - 0.25f, 0.f), 13.f);
      const float cx = fminf(fmaxf((float)Xc * 0.5f - 0.25f, 0.f), 13.f);
      const int y0 = (int)cy; const int y1 = min(y0 + 1, 13); const float fy = cy - (float)y0;
      const int x0 = (int)cx; const int x1 = min(x0 + 1, 13); const float fx = cx - (float)x0;
      const float w00 = (1.f - fy) * (1.f - fx), w01 = (1.f - fy) * fx;
      const float w10 = fy * (1.f - fx),         w11 = fy * fx;
      const int i00 = (y0 * 14 + x0) * 784 + t;
      const int i01 = (y0 * 14 + x1) * 784 + t;
      const int i10 = (y1 * 14 + x0) * 784 + t;
      const int i11 = (y1 * 14 + x1) * 784 + t;
      float F[6];
      #pragma unroll
      for (int o = 0; o < 6; o++) F[o] = bfu[o];
      #pragma unroll
      for (int c = 0; c < 6; c++) {
        const float sv = bf2f(Ssc[c][l][t]);
        const float* rc = ra + (size_t)c * (196 * 784);
        const float rx = w00 * rc[i00] + w01 * rc[i01] + w10 * rc[i10] + w11 * rc[i11];
        #pragma unroll
        for (int o = 0; o < 6; o++) F[o] += wf[o * 12 + c] * sv + wf[o * 12 + 6 + c] * rx;
      }
      #pragma unroll
      for (int o = 0; o < 6; o++) Ssc[o][l][t] = f2bf(F[o]);
    }
  }
  __syncthreads();

  // ---- phase 3: softmax over t per (o,l); store exp, keep row sums ----
  {
    const int wave = tid >> 6, lane = tid & 63;
    for (int r = wave; r < 24; r += 4) {
      ushort_t* row = &Ssc[r >> 2][r & 3][0];
      float m = -1e30f;
      for (int t = lane; t < 784; t += 64) m = fmaxf(m, bf2f(row[t]));
      #pragma unroll
      for (int off = 32; off >= 1; off >>= 1) m = fmaxf(m, __shfl_xor(m, off));
      float s = 0.f;
      for (int t = lane; t < 784; t += 64) {
        const float p = __expf(bf2f(row[t]) - m);
        s += p;
        row[t] = f2bf(p);
      }
      #pragma unroll
      for (int off = 32; off >= 1; off >>= 1) s += __shfl_xor(s, off);
      if (lane == 0) rowsum[r] = s;
    }
  }

  // ---- phase 4: O[o,l,:] = sum_t P[o,l,t] * V[t, o*64:] ----
  float4 acc0 = {0.f, 0.f, 0.f, 0.f}, acc1 = {0.f, 0.f, 0.f, 0.f};
  const int o0 = tid >> 6, al0 = (tid >> 4) & 3, v0 = tid & 15;
  const int id1 = tid + 256;
  const int o1 = id1 >> 6, al1 = (id1 >> 4) & 3, v1 = id1 & 15;
  const bool act1 = (tid < 128);

  for (int kt = 0; kt < 28; kt++) {
    const int t0 = kt * 28;
    __syncthreads();
    {
      const uint4* src = (const uint4*)(Vb + kvbase) + (size_t)t0 * 48;
      for (int i = tid; i < 1344; i += 256) {
        const int r = i / 48, cc = i % 48;
        ((uint4*)&KVs[r][0])[cc] = src[i];
      }
    }
    __syncthreads();
    #pragma unroll 7
    for (int tt = 0; tt < 28; tt++) {
      {
        const float a = bf2f(Ssc[o0][al0][t0 + tt]);
        const uint2 vv = *(const uint2*)&KVs[tt][o0 * 64 + v0 * 4];
        acc0.x += a * bflo(vv.x); acc0.y += a * bfhi(vv.x);
        acc0.z += a * bflo(vv.y); acc0.w += a * bfhi(vv.y);
      }
      if (act1) {
        const float a = bf2f(Ssc[o1][al1][t0 + tt]);
        const uint2 vv = *(const uint2*)&KVs[tt][o1 * 64 + v1 * 4];
        acc1.x += a * bflo(vv.x); acc1.y += a * bfhi(vv.x);
        acc1.z += a * bflo(vv.y); acc1.w += a * bfhi(vv.y);
      }
    }
  }
  {
    const float inv = 1.f / rowsum[o0 * 4 + al0];
    float4 r = {acc0.x * inv, acc0.y * inv, acc0.z * inv, acc0.w * inv};
    *(float4*)&Opre[((size_t)b * 784 + l0 + al0) * 384 + o0 * 64 + v0 * 4] = r;
  }
  if (act1) {
    const float inv = 1.f / rowsum[o1 * 4 + al1];
    float4 r = {acc1.x * inv, acc1.y * inv, acc1.z * inv, acc1.w * inv};
    *(float4*)&Opre[((size_t)b * 784 + l0 + al1) * 384 + o1 * 64 + v1 * 4] = r;
  }
}

// ---------- host launcher ----------
extern "C" void kernel_launch(void* const* d_in, const int* in_sizes, int n_in,
                              void* d_out, int out_size, void* d_ws, size_t ws_size,
                              hipStream_t stream)
{
  const float* x        = (const float*)d_in[0];
  const float* res_attn = (const float*)d_in[1];
  const float* conv_w   = (const float*)d_in[2];
  const float* ln_g     = (const float*)d_in[3];
  const float* ln_b     = (const float*)d_in[4];
  const float* wq       = (const float*)d_in[5];
  const float* wk       = (const float*)d_in[6];
  const float* wv       = (const float*)d_in[7];
  const float* w_proj   = (const float*)d_in[8];
  const float* b_proj   = (const float*)d_in[9];
  const float* w_fuse   = (const float*)d_in[10];
  const float* b_fuse   = (const float*)d_in[11];
  float* out = (float*)d_out;

  // workspace layout (33.7 MB total):
  //   q_ln  f32 [6272,384]   (reused as Opre after Q-GEMM consumes it)
  //   kv    f32 [6272,384]
  //   Qb/Kb/Vb bf16 [6272,384] each
  const size_t NE = (size_t)8 * 784 * 384;
  float* q_ln = (float*)d_ws;
  float* kvb  = q_ln + NE;
  ushort_t* Qb = (ushort_t*)(kvb + NE);
  ushort_t* Kb = Qb + NE;
  ushort_t* Vb = Kb + NE;
  float* Opre = q_ln;

  k_convln<<<dim3(8 * 784), dim3(384), 0, stream>>>(x, conv_w, ln_g, ln_b, q_ln);
  k_pool  <<<dim3(9408),    dim3(256), 0, stream>>>(x, kvb);

  dim3 gg(6, 98), gb(256);
  k_gemm_xt<true,  false><<<gg, gb, 0, stream>>>(q_ln, wq, nullptr, Qb, 6272, 384, 384);
  k_gemm_xt<true,  false><<<gg, gb, 0, stream>>>(kvb,  wk, nullptr, Kb, 6272, 384, 384);
  k_gemm_xt<true,  false><<<gg, gb, 0, stream>>>(kvb,  wv, nullptr, Vb, 6272, 384, 384);

  k_attn<<<dim3(8 * 196), dim3(256), 0, stream>>>(Qb, Kb, Vb, res_attn, w_fuse, b_fuse, Opre);

  k_gemm_xt<false, true><<<gg, gb, 0, stream>>>(Opre, w_proj, b_proj, out, 6272, 384, 384);
}

// Round 3
// 329.648 us; speedup vs baseline: 3.4056x; 3.4056x over previous
//
#include <hip/hip_runtime.h>

typedef unsigned int uint;
typedef unsigned short ushort_t;
typedef short bf16x8 __attribute__((ext_vector_type(8)));
typedef float f32x4 __attribute__((ext_vector_type(4)));

// ---------- bf16 helpers ----------
__device__ __forceinline__ ushort_t f2bf(float f) {
  uint u = __builtin_bit_cast(uint, f);
  u += 0x7fffu + ((u >> 16) & 1u);
  return (ushort_t)(u >> 16);
}
__device__ __forceinline__ float bf2f(ushort_t s) {
  return __builtin_bit_cast(float, (uint)s << 16);
}
__device__ __forceinline__ bf16x8 ld_frag(const ushort_t* p) {
  return __builtin_bit_cast(bf16x8, *(const uint4*)p);
}

// ---------- Kernel 1: depthwise conv 3x3 s2 p1 + LayerNorm -> bf16 ----------
__global__ __launch_bounds__(384) void k_convln(
    const float* __restrict__ x, const float* __restrict__ wc,
    const float* __restrict__ g, const float* __restrict__ bb,
    ushort_t* __restrict__ qout)
{
  const int b  = blockIdx.x / 784;
  const int t  = blockIdx.x % 784;
  const int oy = t / 28, ox = t % 28;
  const int c  = threadIdx.x;
  const float* xb = x + (size_t)b * 3136 * 384 + c;
  float acc = 0.f;
  #pragma unroll
  for (int ky = 0; ky < 3; ky++) {
    const int iy = 2 * oy - 1 + ky;
    if (iy < 0 || iy >= 56) continue;
    #pragma unroll
    for (int kx = 0; kx < 3; kx++) {
      const int ix = 2 * ox - 1 + kx;
      if (ix < 0 || ix >= 56) continue;
      acc += wc[c * 9 + ky * 3 + kx] * xb[(size_t)(iy * 56 + ix) * 384];
    }
  }
  float s = acc, s2 = acc * acc;
  #pragma unroll
  for (int off = 32; off >= 1; off >>= 1) {
    s  += __shfl_xor(s,  off);
    s2 += __shfl_xor(s2, off);
  }
  __shared__ float ps[6], ps2[6];
  if ((c & 63) == 0) { ps[c >> 6] = s; ps2[c >> 6] = s2; }
  __syncthreads();
  float S = 0.f, S2 = 0.f;
  #pragma unroll
  for (int i = 0; i < 6; i++) { S += ps[i]; S2 += ps2[i]; }
  const float mu  = S * (1.f / 384.f);
  const float var = S2 * (1.f / 384.f) - mu * mu;
  const float inv = rsqrtf(var + 1e-5f);
  qout[((size_t)b * 784 + t) * 384 + c] = f2bf((acc - mu) * inv * g[c] + bb[c]);
}

// ---------- Kernel 2: 2x2 average pool -> bf16 ----------
__global__ __launch_bounds__(256) void k_pool(
    const float* __restrict__ x, ushort_t* __restrict__ kvout)
{
  const int idx = blockIdx.x * 256 + threadIdx.x;
  const int c = idx % 384;
  const int t = (idx / 384) % 784;
  const int b = idx / (384 * 784);
  const int ty = t / 28, tx = t % 28;
  const float* xb = x + (size_t)b * 3136 * 384 + c;
  const int r0 = (2 * ty) * 56 + 2 * tx;
  const float v = xb[(size_t)r0 * 384] + xb[(size_t)(r0 + 1) * 384]
                + xb[(size_t)(r0 + 56) * 384] + xb[(size_t)(r0 + 57) * 384];
  kvout[idx] = f2bf(v * 0.25f);
}

// ---------- Kernel 3: weights f32 -> bf16 ----------
__global__ __launch_bounds__(256) void k_wcvt(
    const float* __restrict__ a, const float* __restrict__ b,
    const float* __restrict__ c, const float* __restrict__ d,
    ushort_t* __restrict__ oa, ushort_t* __restrict__ ob,
    ushort_t* __restrict__ oc, ushort_t* __restrict__ od)
{
  const int i = blockIdx.x * 256 + threadIdx.x;
  if (i < 147456) {
    oa[i] = f2bf(a[i]); ob[i] = f2bf(b[i]);
    oc[i] = f2bf(c[i]); od[i] = f2bf(d[i]);
  }
}

// ---------- Kernel 4: dense MFMA GEMM, M=6272 N=384 K=384 ----------
// Y[m,n] = sum_k X[m,k]*W[n,k]. 128x128 tile, 4 waves (2x2), 4x4 16x16 tiles.
// MODE 0: bf16 row-major out; MODE 1: bf16 transposed (b,384,784) out (for V);
// MODE 2: f32 +bias out.
template<int MODE>
__global__ __launch_bounds__(256) void k_gemm(
    const ushort_t* __restrict__ X, const ushort_t* __restrict__ W,
    const float* __restrict__ bias, void* __restrict__ Y)
{
  __shared__ ushort_t As[128][40];  // pad 32->40: row stride 20 words (2-way, free)
  __shared__ ushort_t Bs[128][40];
  const int tid = threadIdx.x, w = tid >> 6, lane = tid & 63;
  const int quad = lane >> 4, r = lane & 15;
  const int m0 = blockIdx.y * 128, n0 = blockIdx.x * 128;
  const int wm = w >> 1, wn = w & 1;
  // staging: 128 rows x 32 bf16 per matrix = 512 8-elem chunks; each of 256
  // threads writes rows lr and lr+64 (fixes R2 bug: half-tile uninitialized)
  const int lr = tid >> 2, lc = (tid & 3) << 3;
  const ushort_t* xp = X + (size_t)(m0 + lr) * 384 + lc;
  const ushort_t* wp = W + (size_t)(n0 + lr) * 384 + lc;
  f32x4 acc[4][4] = {};
  for (int k0 = 0; k0 < 384; k0 += 32) {
    __syncthreads();
    *(uint4*)&As[lr][lc]      = *(const uint4*)(xp + k0);
    *(uint4*)&As[lr + 64][lc] = *(const uint4*)(xp + (size_t)64 * 384 + k0);
    *(uint4*)&Bs[lr][lc]      = *(const uint4*)(wp + k0);
    *(uint4*)&Bs[lr + 64][lc] = *(const uint4*)(wp + (size_t)64 * 384 + k0);
    __syncthreads();
    bf16x8 af[4], bf_[4];
    #pragma unroll
    for (int mt = 0; mt < 4; mt++) af[mt]  = *(const bf16x8*)&As[wm * 64 + mt * 16 + r][quad * 8];
    #pragma unroll
    for (int nt = 0; nt < 4; nt++) bf_[nt] = *(const bf16x8*)&Bs[wn * 64 + nt * 16 + r][quad * 8];
    #pragma unroll
    for (int mt = 0; mt < 4; mt++)
      #pragma unroll
      for (int nt = 0; nt < 4; nt++)
        acc[mt][nt] = __builtin_amdgcn_mfma_f32_16x16x32_bf16(af[mt], bf_[nt], acc[mt][nt], 0, 0, 0);
  }
  #pragma unroll
  for (int mt = 0; mt < 4; mt++) {
    #pragma unroll
    for (int nt = 0; nt < 4; nt++) {
      #pragma unroll
      for (int i = 0; i < 4; i++) {
        const int row = m0 + wm * 64 + mt * 16 + quad * 4 + i;
        const int col = n0 + wn * 64 + nt * 16 + r;
        const float v = acc[mt][nt][i];
        if constexpr (MODE == 2) {
          ((float*)Y)[(size_t)row * 384 + col] = v + bias[col];
        } else if constexpr (MODE == 0) {
          ((ushort_t*)Y)[(size_t)row * 384 + col] = f2bf(v);
        } else {
          const int bb = row / 784, tt = row % 784;
          ((ushort_t*)Y)[((size_t)bb * 384 + col) * 784 + tt] = f2bf(v);
        }
      }
    }
  }
}

// ---------- Kernel 5: QK^T batched MFMA (48 batches, M=N=784, K=64) ----------
// No LDS: K=64 -> 2 k-steps, fragments direct from global (L2-hot).
// S layout: (b, l, c, t) bf16.
__global__ __launch_bounds__(256) void k_qk(
    const ushort_t* __restrict__ Qb, const ushort_t* __restrict__ Kb,
    ushort_t* __restrict__ S)
{
  const int tid = threadIdx.x, w = tid >> 6, lane = tid & 63;
  const int quad = lane >> 4, r = lane & 15;
  const int bh = blockIdx.z, b = bh / 6, h = bh % 6;
  const int m0 = blockIdx.y * 64 + w * 16;
  const int t0 = blockIdx.x * 112;
  const int lq = min(m0 + r, 783);
  const ushort_t* qp = Qb + (size_t)(b * 784 + lq) * 384 + h * 64 + quad * 8;
  const bf16x8 a0 = ld_frag(qp), a1 = ld_frag(qp + 32);
  f32x4 acc[7] = {};
  #pragma unroll
  for (int j = 0; j < 7; j++) {
    const int t = t0 + j * 16 + r;
    const ushort_t* kp = Kb + (size_t)(b * 784 + t) * 384 + h * 64 + quad * 8;
    acc[j] = __builtin_amdgcn_mfma_f32_16x16x32_bf16(a0, ld_frag(kp),      acc[j], 0, 0, 0);
    acc[j] = __builtin_amdgcn_mfma_f32_16x16x32_bf16(a1, ld_frag(kp + 32), acc[j], 0, 0, 0);
  }
  const float scale = 0.05103103630798288f; // 384^-0.5
  #pragma unroll
  for (int j = 0; j < 7; j++) {
    #pragma unroll
    for (int i = 0; i < 4; i++) {
      const int lo = m0 + quad * 4 + i;
      if (lo < 784)
        S[((size_t)(b * 784 + lo) * 6 + h) * 784 + t0 + j * 16 + r] = f2bf(acc[j][i] * scale);
    }
  }
}

// ---------- Kernel 6: fuse heads + bilinear res_attn + softmax (in place) ----
// One block per (b,l). Reads S rows (6x784), writes normalized P at the same
// addresses (each thread touches only its own t columns -> race-free).
__global__ __launch_bounds__(256) void k_fuse(
    ushort_t* __restrict__ S, const float* __restrict__ ra,
    const float* __restrict__ w_fuse, const float* __restrict__ b_fuse)
{
  const int tid = threadIdx.x;
  const int bl = blockIdx.x, b = bl / 784, l = bl % 784;
  __shared__ float wf[72], bfu[6];
  __shared__ float redm[4][6], reds[4][6];
  if (tid < 72) wf[tid] = w_fuse[tid];
  if (tid < 6)  bfu[tid] = b_fuse[tid];
  __syncthreads();

  const int Y = l / 28, X = l % 28;
  const float cy = fminf(fmaxf((float)Y * 0.5f - 0.25f, 0.f), 13.f);
  const float cx = fminf(fmaxf((float)X * 0.5f - 0.25f, 0.f), 13.f);
  const int y0 = (int)cy, y1 = min(y0 + 1, 13);
  const int x0 = (int)cx, x1 = min(x0 + 1, 13);
  const float fy = cy - (float)y0, fx = cx - (float)x0;
  const float w00 = (1.f - fy) * (1.f - fx), w01 = (1.f - fy) * fx;
  const float w10 = fy * (1.f - fx),         w11 = fy * fx;
  const int p00 = (y0 * 14 + x0) * 784, p01 = (y0 * 14 + x1) * 784;
  const int p10 = (y1 * 14 + x0) * 784, p11 = (y1 * 14 + x1) * 784;

  ushort_t* Srow = S + (size_t)bl * 6 * 784;
  const float* rab = ra + (size_t)b * 6 * 196 * 784;

  float F[4][6];
  #pragma unroll
  for (int j = 0; j < 4; j++) {
    const int t = tid + j * 256;
    if (t < 784) {
      float a[6];
      #pragma unroll
      for (int o = 0; o < 6; o++) a[o] = bfu[o];
      #pragma unroll
      for (int c = 0; c < 6; c++) {
        const float* rc = rab + (size_t)c * (196 * 784);
        const float rx = w00 * rc[p00 + t] + w01 * rc[p01 + t]
                       + w10 * rc[p10 + t] + w11 * rc[p11 + t];
        const float sv = bf2f(Srow[c * 784 + t]);
        #pragma unroll
        for (int o = 0; o < 6; o++) a[o] += wf[o * 12 + c] * sv + wf[o * 12 + 6 + c] * rx;
      }
      #pragma unroll
      for (int o = 0; o < 6; o++) F[j][o] = a[o];
    } else {
      #pragma unroll
      for (int o = 0; o < 6; o++) F[j][o] = -1e30f;
    }
  }
  // block max per o
  float mx[6];
  #pragma unroll
  for (int o = 0; o < 6; o++) {
    mx[o] = fmaxf(fmaxf(F[0][o], F[1][o]), fmaxf(F[2][o], F[3][o]));
    #pragma unroll
    for (int off = 32; off >= 1; off >>= 1) mx[o] = fmaxf(mx[o], __shfl_xor(mx[o], off));
  }
  if ((tid & 63) == 0) {
    #pragma unroll
    for (int o = 0; o < 6; o++) redm[tid >> 6][o] = mx[o];
  }
  __syncthreads();
  float M[6];
  #pragma unroll
  for (int o = 0; o < 6; o++)
    M[o] = fmaxf(fmaxf(redm[0][o], redm[1][o]), fmaxf(redm[2][o], redm[3][o]));
  // exp + block sum per o
  float sm[6] = {};
  #pragma unroll
  for (int j = 0; j < 4; j++)
    #pragma unroll
    for (int o = 0; o < 6; o++) {
      const float p = __expf(F[j][o] - M[o]);
      F[j][o] = p; sm[o] += p;
    }
  #pragma unroll
  for (int o = 0; o < 6; o++) {
    #pragma unroll
    for (int off = 32; off >= 1; off >>= 1) sm[o] += __shfl_xor(sm[o], off);
  }
  if ((tid & 63) == 0) {
    #pragma unroll
    for (int o = 0; o < 6; o++) reds[tid >> 6][o] = sm[o];
  }
  __syncthreads();
  float inv[6];
  #pragma unroll
  for (int o = 0; o < 6; o++)
    inv[o] = 1.f / (reds[0][o] + reds[1][o] + reds[2][o] + reds[3][o]);
  #pragma unroll
  for (int j = 0; j < 4; j++) {
    const int t = tid + j * 256;
    if (t < 784) {
      #pragma unroll
      for (int o = 0; o < 6; o++) Srow[o * 784 + t] = f2bf(F[j][o] * inv[o]);
    }
  }
}

// ---------- Kernel 7: PV batched MFMA (48 batches, M=784 N=64 K=784) -------
// P layout (b,l,o,t); Vt layout (b,384,784). Out bf16 (b,784,384).
__global__ __launch_bounds__(256) void k_pv(
    const ushort_t* __restrict__ P, const ushort_t* __restrict__ Vt,
    ushort_t* __restrict__ O)
{
  const int tid = threadIdx.x, w = tid >> 6, lane = tid & 63;
  const int quad = lane >> 4, r = lane & 15;
  const int bo = blockIdx.y, b = bo / 6, o = bo % 6;
  const int m0 = blockIdx.x * 64 + w * 16;
  const int lq = min(m0 + r, 783);
  const ushort_t* ap = P + ((size_t)(b * 784 + lq) * 6 + o) * 784 + quad * 8;
  const ushort_t* bp = Vt + ((size_t)b * 384 + o * 64 + r) * 784 + quad * 8;
  f32x4 acc[4] = {};
  for (int kk = 0; kk < 25; kk++) {
    const int k0 = kk * 32;
    const bool full = (kk < 24) | (quad < 2);  // tail: K rem 16, quads 2,3 -> 0
    bf16x8 af = {}, bf_[4] = {};
    if (full) {
      af = ld_frag(ap + k0);
      #pragma unroll
      for (int nt = 0; nt < 4; nt++) bf_[nt] = ld_frag(bp + (size_t)nt * 16 * 784 + k0);
    }
    #pragma unroll
    for (int nt = 0; nt < 4; nt++)
      acc[nt] = __builtin_amdgcn_mfma_f32_16x16x32_bf16(af, bf_[nt], acc[nt], 0, 0, 0);
  }
  #pragma unroll
  for (int nt = 0; nt < 4; nt++) {
    #pragma unroll
    for (int i = 0; i < 4; i++) {
      const int lo = m0 + quad * 4 + i;
      if (lo < 784)
        O[(size_t)(b * 784 + lo) * 384 + o * 64 + nt * 16 + r] = f2bf(acc[nt][i]);
    }
  }
}

// ---------- host launcher ----------
extern "C" void kernel_launch(void* const* d_in, const int* in_sizes, int n_in,
                              void* d_out, int out_size, void* d_ws, size_t ws_size,
                              hipStream_t stream)
{
  const float* x        = (const float*)d_in[0];
  const float* res_attn = (const float*)d_in[1];
  const float* conv_w   = (const float*)d_in[2];
  const float* ln_g     = (const float*)d_in[3];
  const float* ln_b     = (const float*)d_in[4];
  const float* wq       = (const float*)d_in[5];
  const float* wk       = (const float*)d_in[6];
  const float* wv       = (const float*)d_in[7];
  const float* w_proj   = (const float*)d_in[8];
  const float* b_proj   = (const float*)d_in[9];
  const float* w_fuse   = (const float*)d_in[10];
  const float* b_fuse   = (const float*)d_in[11];
  float* out = (float*)d_out;

  // ws layout (bf16 elements), total ~89 MB
  const size_t NE = (size_t)8 * 784 * 384;      // 2,408,448
  const size_t NW = 147456;
  ushort_t* q_ln_b = (ushort_t*)d_ws;
  ushort_t* kv_b   = q_ln_b + NE;
  ushort_t* Qb     = kv_b + NE;
  ushort_t* Kb     = Qb + NE;
  ushort_t* Vt     = Kb + NE;   // (b, 384, 784)
  ushort_t* Opre   = Vt + NE;
  ushort_t* wqb    = Opre + NE;
  ushort_t* wkb    = wqb + NW;
  ushort_t* wvb    = wkb + NW;
  ushort_t* wpb    = wvb + NW;
  ushort_t* S      = wpb + NW;  // (b, 784, 6, 784) -> becomes P in place

  k_convln<<<dim3(8 * 784), dim3(384), 0, stream>>>(x, conv_w, ln_g, ln_b, q_ln_b);
  k_pool  <<<dim3(9408),    dim3(256), 0, stream>>>(x, kv_b);
  k_wcvt  <<<dim3(576),     dim3(256), 0, stream>>>(wq, wk, wv, w_proj, wqb, wkb, wvb, wpb);

  k_gemm<0><<<dim3(3, 49), dim3(256), 0, stream>>>(q_ln_b, wqb, nullptr, Qb);
  k_gemm<0><<<dim3(3, 49), dim3(256), 0, stream>>>(kv_b,   wkb, nullptr, Kb);
  k_gemm<1><<<dim3(3, 49), dim3(256), 0, stream>>>(kv_b,   wvb, nullptr, Vt);

  k_qk  <<<dim3(7, 13, 48), dim3(256), 0, stream>>>(Qb, Kb, S);
  k_fuse<<<dim3(8 * 784),   dim3(256), 0, stream>>>(S, res_attn, w_fuse, b_fuse);
  k_pv  <<<dim3(13, 48),    dim3(256), 0, stream>>>(S, Vt, Opre);

  k_gemm<2><<<dim3(3, 49), dim3(256), 0, stream>>>(Opre, wpb, b_proj, out);
}